// Round 6
// baseline (506.479 us; speedup 1.0000x reference)
//
#include <hip/hip_runtime.h>
#include <hip/hip_bf16.h>
#include <math.h>

#define DD 128
#define HEADS 8
#define HID 16
#define NEG_SLOPE 0.2f
#define N_LAYERS 5
#define N_GRAPHS 64
#define N_CLASSES 10
#define NBINS 256
#define BIN_CAP 8192

typedef __bf16 bf16x8 __attribute__((ext_vector_type(8)));
typedef float f32x4 __attribute__((ext_vector_type(4)));

__device__ __forceinline__ float bflo(unsigned u) { return __uint_as_float(u << 16); }
__device__ __forceinline__ float bfhi(unsigned u) { return __uint_as_float(u & 0xffff0000u); }
__device__ __forceinline__ float bf1(unsigned short us) { return __uint_as_float(((unsigned)us) << 16); }
// float -> bf16 (round-to-nearest-even), bit-twiddle; finite inputs only
__device__ __forceinline__ unsigned short f2bf(float f) {
    unsigned u = __float_as_uint(f);
    u += 0x7fffu + ((u >> 16) & 1u);
    return (unsigned short)(u >> 16);
}
__device__ __forceinline__ unsigned pack2bf(float a, float b) {
    return (unsigned)f2bf(a) | ((unsigned)f2bf(b) << 16);
}

#define WCNT (N_LAYERS * 4 * 16 * 64)   // wprep thread count (20480)

// ---------------- fused setup: convert x->bf16 | weight swizzle | zero pooled/counts ----

__global__ void k_setup(const float* __restrict__ x, unsigned* __restrict__ xb,
                        const float* __restrict__ Wl, const float* __restrict__ Wr,
                        unsigned short* __restrict__ wB,
                        float* __restrict__ pooled, float* __restrict__ counts, int n2) {
    int id = blockIdx.x * 256 + threadIdx.x;
    if (id < n2) {                                   // x -> bf16 (packed pairs)
        float2 v = *(const float2*)(x + 2 * (size_t)id);
        xb[id] = pack2bf(v.x, v.y);
        return;
    }
    id -= n2;
    if (id < WCNT) {                                 // weight swizzle
        int lane = id & 63;
        int ntg  = (id >> 6) & 15;
        int ks   = (id >> 10) & 3;
        int l    = id >> 12;
        int q = lane >> 4, r = lane & 15;
        int n = ntg * 16 + r;
        const float* W = ((n < DD) ? Wl : Wr) + (size_t)l * DD * DD;
        int nn = n & (DD - 1);
        size_t off = (size_t)l * (4 * 16 * 64 * 8) + ((size_t)(ks * 16 + ntg) * 64 + lane) * 8;
        for (int j = 0; j < 8; ++j) {
            int k = ks * 32 + q * 8 + j;
            wB[off + j] = f2bf(W[(size_t)k * DD + nn]);
        }
        return;
    }
    id -= WCNT;
    if (id < N_GRAPHS * DD) { pooled[id] = 0.f; return; }
    id -= N_GRAPHS * DD;
    if (id < N_GRAPHS) counts[id] = 0.f;
}

// ---------------- binned CSR build ----------------
// bin(d) = (d * bin_mul) >> 32 ; lo(b) = ceil(b*2^32 / bin_mul)

__global__ __launch_bounds__(256) void k_bin_cnt(const int* __restrict__ ei,
        int* __restrict__ cnt, int n_edges, int n_total, int chunk,
        unsigned long long bin_mul) {
    __shared__ int hist[NBINS];
    int tid = threadIdx.x;
    hist[tid] = 0;
    __syncthreads();
    int beg = blockIdx.x * chunk;
    int end = beg + chunk; if (end > n_total) end = n_total;
    for (int e = beg + tid; e < end; e += 256) {
        int d = (e < n_edges) ? ei[n_edges + e] : (e - n_edges);
        int b = (int)(((unsigned long long)(unsigned)d * bin_mul) >> 32);
        atomicAdd(&hist[b], 1);
    }
    __syncthreads();
    cnt[tid * 256 + blockIdx.x] = hist[tid];   // cnt[bin][blk]
}

// block per bin: exclusive scan of the 256 per-block counts (in place), emit bin total
__global__ __launch_bounds__(256) void k_bin_scan(int* __restrict__ cnt, int* __restrict__ btot) {
    __shared__ int wsum[4];
    int b = blockIdx.x, t = threadIdx.x, wv = t >> 6, ln = t & 63;
    int v = cnt[b * 256 + t];
    int x = v;
#pragma unroll
    for (int ofs = 1; ofs < 64; ofs <<= 1) {
        int tt = __shfl_up(x, ofs);
        if (ln >= ofs) x += tt;
    }
    if (ln == 63) wsum[wv] = x;
    __syncthreads();
    int off = 0;
    for (int k = 0; k < wv; k++) off += wsum[k];
    int incl = off + x;
    cnt[b * 256 + t] = incl - v;
    if (t == 255) btot[b] = incl;
}

// single block: exclusive scan of 256 bin totals -> bin_start[257]; row_ptr[n]=total
__global__ __launch_bounds__(256) void k_tot_scan(const int* __restrict__ btot,
        int* __restrict__ bin_start, int* __restrict__ row_ptr, int n_nodes) {
    __shared__ int wsum[4];
    int t = threadIdx.x, wv = t >> 6, ln = t & 63;
    int v = btot[t];
    int x = v;
#pragma unroll
    for (int ofs = 1; ofs < 64; ofs <<= 1) {
        int tt = __shfl_up(x, ofs);
        if (ln >= ofs) x += tt;
    }
    if (ln == 63) wsum[wv] = x;
    __syncthreads();
    int off = 0;
    for (int k = 0; k < wv; k++) off += wsum[k];
    int incl = off + x;
    bin_start[t] = incl - v;
    if (t == 255) { bin_start[256] = incl; row_ptr[n_nodes] = incl; }
}

// re-read edges, write packed (src | dst<<16) into per-(block,bin) contiguous runs
__global__ __launch_bounds__(256) void k_bin_scatter(const int* __restrict__ ei,
        const int* __restrict__ cnt, const int* __restrict__ bin_start,
        unsigned* __restrict__ binned, int n_edges, int n_total, int chunk,
        unsigned long long bin_mul) {
    __shared__ int cur[NBINS];
    int tid = threadIdx.x;
    cur[tid] = bin_start[tid] + cnt[tid * 256 + blockIdx.x];
    __syncthreads();
    int beg = blockIdx.x * chunk;
    int end = beg + chunk; if (end > n_total) end = n_total;
    for (int e = beg + tid; e < end; e += 256) {
        int s, d;
        if (e < n_edges) { s = ei[e]; d = ei[n_edges + e]; }
        else { s = d = e - n_edges; }
        int b = (int)(((unsigned long long)(unsigned)d * bin_mul) >> 32);
        int pos = atomicAdd(&cur[b], 1);
        binned[pos] = (unsigned)s | ((unsigned)d << 16);
    }
}

// block per bin: LDS degree count -> scan -> LDS scatter -> coalesced csr_src + row_ptr
__global__ __launch_bounds__(256) void k_bin_csr(const unsigned* __restrict__ binned,
        const int* __restrict__ bin_start, int* __restrict__ csr_src,
        int* __restrict__ row_ptr, int n_nodes, unsigned long long bin_mul) {
    __shared__ int sbuf[BIN_CAP];
    __shared__ int ldeg[256];
    __shared__ int wsum[4];
    int b = blockIdx.x, t = threadIdx.x, wv = t >> 6, ln = t & 63;
    int lo = (int)(((((unsigned long long)b) << 32) + bin_mul - 1) / bin_mul);
    int hi = (int)(((((unsigned long long)(b + 1)) << 32) + bin_mul - 1) / bin_mul);
    if (hi > n_nodes) hi = n_nodes;
    int estart = bin_start[b], eend = bin_start[b + 1];
    int ne = eend - estart;
    ldeg[t] = 0;
    __syncthreads();
    for (int k = t; k < ne; k += 256) {
        unsigned v = binned[estart + k];
        atomicAdd(&ldeg[(int)(v >> 16) - lo], 1);
    }
    __syncthreads();
    int vdeg = ldeg[t];
    int x = vdeg;
#pragma unroll
    for (int ofs = 1; ofs < 64; ofs <<= 1) {
        int tt = __shfl_up(x, ofs);
        if (ln >= ofs) x += tt;
    }
    if (ln == 63) wsum[wv] = x;
    __syncthreads();
    int off = 0;
    for (int k = 0; k < wv; k++) off += wsum[k];
    int excl = off + x - vdeg;
    if (lo + t < hi) row_ptr[lo + t] = estart + excl;
    ldeg[t] = excl;                      // reuse as cursor
    __syncthreads();
    for (int k = t; k < ne; k += 256) {
        unsigned v = binned[estart + k];
        int pos = atomicAdd(&ldeg[(int)(v >> 16) - lo], 1);
        sbuf[pos] = (int)(v & 0xffffu);
    }
    __syncthreads();
    for (int k = t; k < ne; k += 256)
        csr_src[estart + k] = sbuf[k];
}

// ---------------- MFMA GEMM (pure bf16): [xl|xr] = in @ [Wl|Wr] + [bl|br] -------
// Swapped operands: acc = mfma(W-frag, in-frag) = out^T; 4 regs = 4 consecutive
// output columns of one node -> 8B packed stores (round-1 win, kept).

__global__ __launch_bounds__(256) void k_gemm_mfma(
    const unsigned short* __restrict__ in, const unsigned short* __restrict__ wB,
    const float* __restrict__ bl, const float* __restrict__ br,
    unsigned short* __restrict__ xl, unsigned short* __restrict__ xr, int n_nodes) {
    int w = threadIdx.x >> 6;
    int lane = threadIdx.x & 63;
    int q = lane >> 4, r = lane & 15;
    int blk = blockIdx.x;

    f32x4 acc[4][4] = {};
#pragma unroll
    for (int ks = 0; ks < 4; ++ks) {
        bf16x8 bh[4];
#pragma unroll
        for (int nt = 0; nt < 4; ++nt) {
            int ntg = w * 4 + nt;
            bh[nt] = *(const bf16x8*)(wB + ((size_t)(ks * 16 + ntg) * 64 + lane) * 8);
        }
        bf16x8 ah[4];
#pragma unroll
        for (int mt = 0; mt < 4; ++mt) {
            int node = blk * 64 + mt * 16 + r;
            if (node >= n_nodes) node = n_nodes - 1;   // clamp; stores guarded
            ah[mt] = *(const bf16x8*)(in + (size_t)node * DD + ks * 32 + q * 8);
        }
#pragma unroll
        for (int mt = 0; mt < 4; ++mt)
#pragma unroll
            for (int nt = 0; nt < 4; ++nt)
                acc[mt][nt] = __builtin_amdgcn_mfma_f32_16x16x32_bf16(bh[nt], ah[mt], acc[mt][nt], 0, 0, 0);
    }
    // out^T fragment: node = blk*64 + mt*16 + (lane&15); col = cb + nt*16 + q*4 + reg
    bool wl = (w < 2);
    unsigned short* base = wl ? xl : xr;
    const float* bsrc = wl ? bl : br;
    int cb = (w & 1) * 64;
#pragma unroll
    for (int nt = 0; nt < 4; ++nt) {
        int cm = cb + nt * 16 + q * 4;               // column within [0,128)
        float4 bv = *(const float4*)(bsrc + cm);
#pragma unroll
        for (int mt = 0; mt < 4; ++mt) {
            int node = blk * 64 + mt * 16 + r;
            if (node < n_nodes) {
                uint2 o;
                o.x = pack2bf(acc[mt][nt][0] + bv.x, acc[mt][nt][1] + bv.y);
                o.y = pack2bf(acc[mt][nt][2] + bv.z, acc[mt][nt][3] + bv.w);
                *(uint2*)(base + (size_t)node * DD + cm) = o;
            }
        }
    }
}

// ---------------- per-node aggregation: plain-exp softmax, 4 edges/iter ----------
// Latency-bound random gather (round 2/3/4 lesson: dur tracks hbm_bytes at
// ~2.3 TB/s effective): 2-deep gather prefetch + branchless clamped indexing
// to double outstanding loads per wave. Arithmetic identical to the 45.2us body.

__global__ __launch_bounds__(256) void k_node_agg(
    const unsigned short* __restrict__ xl, const unsigned short* __restrict__ xr,
    const int* __restrict__ row_ptr, const int* __restrict__ csr_src,
    const float* __restrict__ att, const float* __restrict__ bias,
    unsigned short* __restrict__ h_out, int n_nodes) {
    int wave = threadIdx.x >> 6;
    int lane = threadIdx.x & 63;
    int node = blockIdx.x * 4 + wave;
    if (node >= n_nodes) return;
    int grp = lane >> 4, sl = lane & 15;
    int beg = row_ptr[node], end = row_ptr[node + 1];
    int last = end - 1;                 // degree >= 1 (self loop), so last >= beg

    uint4 xru = *(const uint4*)(xr + (size_t)node * DD + sl * 8);
    float xr0 = bflo(xru.x), xr1 = bfhi(xru.x), xr2 = bflo(xru.y), xr3 = bfhi(xru.y);
    float xr4 = bflo(xru.z), xr5 = bfhi(xru.z), xr6 = bflo(xru.w), xr7 = bfhi(xru.w);
    float4 at0 = *(const float4*)(att + sl * 8);
    float4 at1 = *(const float4*)(att + sl * 8 + 4);

    float l = 0.f;
    float a0 = 0.f, a1 = 0.f, a2 = 0.f, a3 = 0.f, a4 = 0.f, a5 = 0.f, a6 = 0.f, a7 = 0.f;

    int t0 = beg + grp;
    // branchless 2-deep pipeline: cur(t) in xu0, t+4 in xu1, index for t+8 in s2
    int s0 = csr_src[min(t0, last)];
    int s1 = csr_src[min(t0 + 4, last)];
    int s2 = csr_src[min(t0 + 8, last)];
    uint4 xu0 = *(const uint4*)(xl + (size_t)s0 * DD + sl * 8);
    uint4 xu1 = *(const uint4*)(xl + (size_t)s1 * DD + sl * 8);

    for (int t = t0; t < end; t += 4) {
        uint4 cur = xu0;
        xu0 = xu1;
        xu1 = *(const uint4*)(xl + (size_t)s2 * DD + sl * 8);   // gather t+8
        s2 = csr_src[min(t + 12, last)];                        // index t+12

        float x0 = bflo(cur.x), x1 = bfhi(cur.x), x2 = bflo(cur.y), x3 = bfhi(cur.y);
        float x4 = bflo(cur.z), x5 = bfhi(cur.z), x6 = bflo(cur.w), x7 = bfhi(cur.w);
        float v0 = x0 + xr0; v0 = v0 > 0.f ? v0 : NEG_SLOPE * v0;
        float v1 = x1 + xr1; v1 = v1 > 0.f ? v1 : NEG_SLOPE * v1;
        float v2 = x2 + xr2; v2 = v2 > 0.f ? v2 : NEG_SLOPE * v2;
        float v3 = x3 + xr3; v3 = v3 > 0.f ? v3 : NEG_SLOPE * v3;
        float v4 = x4 + xr4; v4 = v4 > 0.f ? v4 : NEG_SLOPE * v4;
        float v5 = x5 + xr5; v5 = v5 > 0.f ? v5 : NEG_SLOPE * v5;
        float v6 = x6 + xr6; v6 = v6 > 0.f ? v6 : NEG_SLOPE * v6;
        float v7 = x7 + xr7; v7 = v7 > 0.f ? v7 : NEG_SLOPE * v7;
        float lg = at0.x * v0 + at0.y * v1 + at0.z * v2 + at0.w * v3 +
                   at1.x * v4 + at1.y * v5 + at1.z * v6 + at1.w * v7;
        lg += __shfl_xor(lg, 1);           // head logit (lanes 2h,2h+1)
        float p = __expf(lg);
        l += p;
        a0 += p * x0; a1 += p * x1; a2 += p * x2; a3 += p * x3;
        a4 += p * x4; a5 += p * x5; a6 += p * x6; a7 += p * x7;
    }
    // merge the 4 edge-groups (plain sums)
    l  += __shfl_xor(l, 16);  l  += __shfl_xor(l, 32);
    a0 += __shfl_xor(a0, 16); a0 += __shfl_xor(a0, 32);
    a1 += __shfl_xor(a1, 16); a1 += __shfl_xor(a1, 32);
    a2 += __shfl_xor(a2, 16); a2 += __shfl_xor(a2, 32);
    a3 += __shfl_xor(a3, 16); a3 += __shfl_xor(a3, 32);
    a4 += __shfl_xor(a4, 16); a4 += __shfl_xor(a4, 32);
    a5 += __shfl_xor(a5, 16); a5 += __shfl_xor(a5, 32);
    a6 += __shfl_xor(a6, 16); a6 += __shfl_xor(a6, 32);
    a7 += __shfl_xor(a7, 16); a7 += __shfl_xor(a7, 32);

    if (grp == 0) {
        float4 bv0 = *(const float4*)(bias + sl * 8);
        float4 bv1 = *(const float4*)(bias + sl * 8 + 4);
        float rl = 1.f / l;
        float o0 = a0 * rl + bv0.x; o0 = o0 > 0.f ? o0 : __expf(o0) - 1.f;
        float o1 = a1 * rl + bv0.y; o1 = o1 > 0.f ? o1 : __expf(o1) - 1.f;
        float o2 = a2 * rl + bv0.z; o2 = o2 > 0.f ? o2 : __expf(o2) - 1.f;
        float o3 = a3 * rl + bv0.w; o3 = o3 > 0.f ? o3 : __expf(o3) - 1.f;
        float o4 = a4 * rl + bv1.x; o4 = o4 > 0.f ? o4 : __expf(o4) - 1.f;
        float o5 = a5 * rl + bv1.y; o5 = o5 > 0.f ? o5 : __expf(o5) - 1.f;
        float o6 = a6 * rl + bv1.z; o6 = o6 > 0.f ? o6 : __expf(o6) - 1.f;
        float o7 = a7 * rl + bv1.w; o7 = o7 > 0.f ? o7 : __expf(o7) - 1.f;
        uint4 o;
        o.x = pack2bf(o0, o1); o.y = pack2bf(o2, o3);
        o.z = pack2bf(o4, o5); o.w = pack2bf(o6, o7);
        *(uint4*)(h_out + (size_t)node * DD + sl * 8) = o;
    }
}

// ---------------- pooling + head ----------------

__global__ void k_pool2(const unsigned short* __restrict__ h, const int* __restrict__ batch,
                        float* __restrict__ pooled, float* __restrict__ counts,
                        int n_nodes, int chunk) {
    int c = threadIdx.x;               // 0..127
    int beg = blockIdx.x * chunk;
    if (beg >= n_nodes) return;
    int end = beg + chunk; if (end > n_nodes) end = n_nodes;
    int cur = batch[beg];
    float acc = 0.f; int cnt = 0;
    for (int node = beg; node < end; ++node) {
        int g = batch[node];
        if (g != cur) {
            atomicAdd(&pooled[cur * DD + c], acc);
            if (c == 0) atomicAdd(&counts[cur], (float)cnt);
            acc = 0.f; cnt = 0; cur = g;
        }
        acc += bf1(h[(size_t)node * DD + c]);
        cnt++;
    }
    atomicAdd(&pooled[cur * DD + c], acc);
    if (c == 0) atomicAdd(&counts[cur], (float)cnt);
}

__global__ void k_final(const float* __restrict__ pooled, const float* __restrict__ counts,
                        const float* __restrict__ Wout, const float* __restrict__ bout,
                        float* __restrict__ out) {
    __shared__ float slog[N_GRAPHS * N_CLASSES];
    int t = threadIdx.x;
    int g = t / N_CLASSES, c = t % N_CLASSES;
    float cnt = fmaxf(counts[g], 1.f);
    float acc = bout[c];
    for (int k = 0; k < DD; k++)
        acc += (pooled[g * DD + k] / cnt) * Wout[k * N_CLASSES + c];
    slog[t] = acc;
    __syncthreads();
    float mx = -INFINITY;
    for (int j = 0; j < N_CLASSES; j++) mx = fmaxf(mx, slog[g * N_CLASSES + j]);
    float se = 0.f;
    for (int j = 0; j < N_CLASSES; j++) se += __expf(slog[g * N_CLASSES + j] - mx);
    out[t] = acc - mx - __logf(se);
}

extern "C" void kernel_launch(void* const* d_in, const int* in_sizes, int n_in,
                              void* d_out, int out_size, void* d_ws, size_t ws_size,
                              hipStream_t stream) {
    const float* x     = (const float*)d_in[0];
    const int*   ei    = (const int*)d_in[1];
    const int*   batch = (const int*)d_in[2];
    const float* Wl    = (const float*)d_in[3];
    const float* bl    = (const float*)d_in[4];
    const float* Wr    = (const float*)d_in[5];
    const float* br    = (const float*)d_in[6];
    const float* att   = (const float*)d_in[7];
    const float* bias  = (const float*)d_in[8];
    const float* Wout  = (const float*)d_in[9];
    const float* bout  = (const float*)d_in[10];
    float* out = (float*)d_out;

    int n_nodes = in_sizes[0] / DD;    // 50000
    int n_edges = in_sizes[1] / 2;     // 800000
    int n_total = n_edges + n_nodes;   // 850000 (with self loops)
    int ND = n_nodes * DD;             // 6.4M

    const int WPL = 4 * 16 * 64 * 8;   // 32768 bf16 per layer
    unsigned long long bin_mul = (((unsigned long long)NBINS) << 32) / (unsigned)n_nodes;

    // workspace: hb | xb | xlb | xrb (bf16) | wB | cnt | btot | bin_start | binned |
    //            csr_src | row_ptr | pooled | counts
    unsigned short* hb  = (unsigned short*)d_ws;
    unsigned short* xb  = hb + (size_t)ND;
    unsigned short* xlb = xb + (size_t)ND;
    unsigned short* xrb = xlb + (size_t)ND;
    unsigned short* wB  = xrb + (size_t)ND;
    int*      cnt       = (int*)(wB + (size_t)N_LAYERS * WPL);
    int*      btot      = cnt + NBINS * 256;
    int*      bin_start = btot + NBINS;
    unsigned* binned    = (unsigned*)(bin_start + NBINS + 1);
    int*      csr_src   = (int*)(binned + n_total);
    int*      row_ptr   = csr_src + n_total;
    float*    pooled    = (float*)(row_ptr + n_nodes + 1);
    float*    counts    = pooled + N_GRAPHS * DD;

    dim3 b256(256);
    int gGemm = (n_nodes + 63) / 64;
    int gAgg  = (n_nodes + 3) / 4;
    int chunk = (n_total + 255) / 256;
    int poolBlocks = 1024;
    int poolChunk = (n_nodes + poolBlocks - 1) / poolBlocks;

    int n2 = ND / 2;
    int setupTotal = n2 + WCNT + N_GRAPHS * DD + N_GRAPHS;
    k_setup<<<(setupTotal + 255) / 256, b256, 0, stream>>>(x, (unsigned*)xb, Wl, Wr, wB,
                                                           pooled, counts, n2);
    k_bin_cnt<<<256, b256, 0, stream>>>(ei, cnt, n_edges, n_total, chunk, bin_mul);
    k_bin_scan<<<NBINS, b256, 0, stream>>>(cnt, btot);
    k_tot_scan<<<1, b256, 0, stream>>>(btot, bin_start, row_ptr, n_nodes);
    k_bin_scatter<<<256, b256, 0, stream>>>(ei, cnt, bin_start, binned, n_edges, n_total,
                                            chunk, bin_mul);
    k_bin_csr<<<NBINS, b256, 0, stream>>>(binned, bin_start, csr_src, row_ptr, n_nodes, bin_mul);

    for (int l = 0; l < N_LAYERS; l++) {
        const float* bl_l   = bl   + (size_t)l * DD;
        const float* br_l   = br   + (size_t)l * DD;
        const float* att_l  = att  + (size_t)l * HEADS * HID;
        const float* bias_l = bias + (size_t)l * DD;
        const unsigned short* in = (l == 0) ? xb : hb;

        k_gemm_mfma<<<gGemm, b256, 0, stream>>>(in, wB + (size_t)l * WPL, bl_l, br_l,
                                                xlb, xrb, n_nodes);
        k_node_agg<<<gAgg, b256, 0, stream>>>(xlb, xrb, row_ptr, csr_src, att_l, bias_l, hb, n_nodes);
    }

    k_pool2<<<poolBlocks, dim3(128), 0, stream>>>(hb, batch, pooled, counts, n_nodes, poolChunk);
    k_final<<<1, dim3(N_GRAPHS * N_CLASSES), 0, stream>>>(pooled, counts, Wout, bout, out);
}

// Round 7
// 472.807 us; speedup vs baseline: 1.0712x; 1.0712x over previous
//
#include <hip/hip_runtime.h>
#include <hip/hip_bf16.h>
#include <math.h>

#define DD 128
#define HEADS 8
#define HID 16
#define NEG_SLOPE 0.2f
#define N_LAYERS 5
#define N_GRAPHS 64
#define N_CLASSES 10
#define NBINS 256
#define BIN_CAP 8192

typedef __bf16 bf16x8 __attribute__((ext_vector_type(8)));
typedef float f32x4 __attribute__((ext_vector_type(4)));

__device__ __forceinline__ float bflo(unsigned u) { return __uint_as_float(u << 16); }
__device__ __forceinline__ float bfhi(unsigned u) { return __uint_as_float(u & 0xffff0000u); }
__device__ __forceinline__ float bf1(unsigned short us) { return __uint_as_float(((unsigned)us) << 16); }
// float -> bf16 (round-to-nearest-even), bit-twiddle; finite inputs only
__device__ __forceinline__ unsigned short f2bf(float f) {
    unsigned u = __float_as_uint(f);
    u += 0x7fffu + ((u >> 16) & 1u);
    return (unsigned short)(u >> 16);
}
__device__ __forceinline__ unsigned pack2bf(float a, float b) {
    return (unsigned)f2bf(a) | ((unsigned)f2bf(b) << 16);
}

#define WCNT (N_LAYERS * 4 * 16 * 64)   // wprep thread count (20480)

// ---------------- fused setup: convert x->bf16 | weight swizzle | zero pooled/counts ----

__global__ void k_setup(const float* __restrict__ x, unsigned* __restrict__ xb,
                        const float* __restrict__ Wl, const float* __restrict__ Wr,
                        unsigned short* __restrict__ wB,
                        float* __restrict__ pooled, float* __restrict__ counts, int n2) {
    int id = blockIdx.x * 256 + threadIdx.x;
    if (id < n2) {                                   // x -> bf16 (packed pairs)
        float2 v = *(const float2*)(x + 2 * (size_t)id);
        xb[id] = pack2bf(v.x, v.y);
        return;
    }
    id -= n2;
    if (id < WCNT) {                                 // weight swizzle
        int lane = id & 63;
        int ntg  = (id >> 6) & 15;
        int ks   = (id >> 10) & 3;
        int l    = id >> 12;
        int q = lane >> 4, r = lane & 15;
        int n = ntg * 16 + r;
        const float* W = ((n < DD) ? Wl : Wr) + (size_t)l * DD * DD;
        int nn = n & (DD - 1);
        size_t off = (size_t)l * (4 * 16 * 64 * 8) + ((size_t)(ks * 16 + ntg) * 64 + lane) * 8;
        for (int j = 0; j < 8; ++j) {
            int k = ks * 32 + q * 8 + j;
            wB[off + j] = f2bf(W[(size_t)k * DD + nn]);
        }
        return;
    }
    id -= WCNT;
    if (id < N_GRAPHS * DD) { pooled[id] = 0.f; return; }
    id -= N_GRAPHS * DD;
    if (id < N_GRAPHS) counts[id] = 0.f;
}

// ---------------- binned CSR build ----------------
// bin(d) = (d * bin_mul) >> 32 ; lo(b) = ceil(b*2^32 / bin_mul)

__global__ __launch_bounds__(256) void k_bin_cnt(const int* __restrict__ ei,
        int* __restrict__ cnt, int n_edges, int n_total, int chunk,
        unsigned long long bin_mul) {
    __shared__ int hist[NBINS];
    int tid = threadIdx.x;
    hist[tid] = 0;
    __syncthreads();
    int beg = blockIdx.x * chunk;
    int end = beg + chunk; if (end > n_total) end = n_total;
    for (int e = beg + tid; e < end; e += 256) {
        int d = (e < n_edges) ? ei[n_edges + e] : (e - n_edges);
        int b = (int)(((unsigned long long)(unsigned)d * bin_mul) >> 32);
        atomicAdd(&hist[b], 1);
    }
    __syncthreads();
    cnt[tid * 256 + blockIdx.x] = hist[tid];   // cnt[bin][blk]
}

// block per bin: exclusive scan of the 256 per-block counts (in place), emit bin total
__global__ __launch_bounds__(256) void k_bin_scan(int* __restrict__ cnt, int* __restrict__ btot) {
    __shared__ int wsum[4];
    int b = blockIdx.x, t = threadIdx.x, wv = t >> 6, ln = t & 63;
    int v = cnt[b * 256 + t];
    int x = v;
#pragma unroll
    for (int ofs = 1; ofs < 64; ofs <<= 1) {
        int tt = __shfl_up(x, ofs);
        if (ln >= ofs) x += tt;
    }
    if (ln == 63) wsum[wv] = x;
    __syncthreads();
    int off = 0;
    for (int k = 0; k < wv; k++) off += wsum[k];
    int incl = off + x;
    cnt[b * 256 + t] = incl - v;
    if (t == 255) btot[b] = incl;
}

// single block: exclusive scan of 256 bin totals -> bin_start[257]; row_ptr[n]=total
__global__ __launch_bounds__(256) void k_tot_scan(const int* __restrict__ btot,
        int* __restrict__ bin_start, int* __restrict__ row_ptr, int n_nodes) {
    __shared__ int wsum[4];
    int t = threadIdx.x, wv = t >> 6, ln = t & 63;
    int v = btot[t];
    int x = v;
#pragma unroll
    for (int ofs = 1; ofs < 64; ofs <<= 1) {
        int tt = __shfl_up(x, ofs);
        if (ln >= ofs) x += tt;
    }
    if (ln == 63) wsum[wv] = x;
    __syncthreads();
    int off = 0;
    for (int k = 0; k < wv; k++) off += wsum[k];
    int incl = off + x;
    bin_start[t] = incl - v;
    if (t == 255) { bin_start[256] = incl; row_ptr[n_nodes] = incl; }
}

// re-read edges, write packed (src | dst<<16) into per-(block,bin) contiguous runs
__global__ __launch_bounds__(256) void k_bin_scatter(const int* __restrict__ ei,
        const int* __restrict__ cnt, const int* __restrict__ bin_start,
        unsigned* __restrict__ binned, int n_edges, int n_total, int chunk,
        unsigned long long bin_mul) {
    __shared__ int cur[NBINS];
    int tid = threadIdx.x;
    cur[tid] = bin_start[tid] + cnt[tid * 256 + blockIdx.x];
    __syncthreads();
    int beg = blockIdx.x * chunk;
    int end = beg + chunk; if (end > n_total) end = n_total;
    for (int e = beg + tid; e < end; e += 256) {
        int s, d;
        if (e < n_edges) { s = ei[e]; d = ei[n_edges + e]; }
        else { s = d = e - n_edges; }
        int b = (int)(((unsigned long long)(unsigned)d * bin_mul) >> 32);
        int pos = atomicAdd(&cur[b], 1);
        binned[pos] = (unsigned)s | ((unsigned)d << 16);
    }
}

// block per bin: LDS degree count -> scan -> LDS scatter -> coalesced csr_src + row_ptr
__global__ __launch_bounds__(256) void k_bin_csr(const unsigned* __restrict__ binned,
        const int* __restrict__ bin_start, int* __restrict__ csr_src,
        int* __restrict__ row_ptr, int n_nodes, unsigned long long bin_mul) {
    __shared__ int sbuf[BIN_CAP];
    __shared__ int ldeg[256];
    __shared__ int wsum[4];
    int b = blockIdx.x, t = threadIdx.x, wv = t >> 6, ln = t & 63;
    int lo = (int)(((((unsigned long long)b) << 32) + bin_mul - 1) / bin_mul);
    int hi = (int)(((((unsigned long long)(b + 1)) << 32) + bin_mul - 1) / bin_mul);
    if (hi > n_nodes) hi = n_nodes;
    int estart = bin_start[b], eend = bin_start[b + 1];
    int ne = eend - estart;
    ldeg[t] = 0;
    __syncthreads();
    for (int k = t; k < ne; k += 256) {
        unsigned v = binned[estart + k];
        atomicAdd(&ldeg[(int)(v >> 16) - lo], 1);
    }
    __syncthreads();
    int vdeg = ldeg[t];
    int x = vdeg;
#pragma unroll
    for (int ofs = 1; ofs < 64; ofs <<= 1) {
        int tt = __shfl_up(x, ofs);
        if (ln >= ofs) x += tt;
    }
    if (ln == 63) wsum[wv] = x;
    __syncthreads();
    int off = 0;
    for (int k = 0; k < wv; k++) off += wsum[k];
    int excl = off + x - vdeg;
    if (lo + t < hi) row_ptr[lo + t] = estart + excl;
    ldeg[t] = excl;                      // reuse as cursor
    __syncthreads();
    for (int k = t; k < ne; k += 256) {
        unsigned v = binned[estart + k];
        int pos = atomicAdd(&ldeg[(int)(v >> 16) - lo], 1);
        sbuf[pos] = (int)(v & 0xffffu);
    }
    __syncthreads();
    for (int k = t; k < ne; k += 256)
        csr_src[estart + k] = sbuf[k];
}

// ---------------- MFMA GEMM (pure bf16): [xl|xr] = in @ [Wl|Wr] + [bl|br] -------
// Swapped operands (round-1 win): acc = mfma(W-frag, in-frag) = out^T.
// Split-N (round 6): gridDim.y = 2; y=0 computes xl (Wl cols), y=1 computes xr.
// 1564 blocks / 6256 waves (~76% occ) vs 782/3128 (~38%) -- the GEMM was
// latency-bound on L2 loads at low occupancy, ~40us/dispatch by wall subtraction.

__global__ __launch_bounds__(256) void k_gemm_mfma(
    const unsigned short* __restrict__ in, const unsigned short* __restrict__ wB,
    const float* __restrict__ bl, const float* __restrict__ br,
    unsigned short* __restrict__ xl, unsigned short* __restrict__ xr, int n_nodes) {
    int w = threadIdx.x >> 6;
    int lane = threadIdx.x & 63;
    int q = lane >> 4, r = lane & 15;
    int blk = blockIdx.x;
    int half = blockIdx.y;               // 0 = xl half, 1 = xr half

    f32x4 acc[4][2] = {};
#pragma unroll
    for (int ks = 0; ks < 4; ++ks) {
        bf16x8 bh[2];
#pragma unroll
        for (int nt = 0; nt < 2; ++nt) {
            int ntg = half * 8 + w * 2 + nt;         // 16-col group within [0,16)
            bh[nt] = *(const bf16x8*)(wB + ((size_t)(ks * 16 + ntg) * 64 + lane) * 8);
        }
        bf16x8 ah[4];
#pragma unroll
        for (int mt = 0; mt < 4; ++mt) {
            int node = blk * 64 + mt * 16 + r;
            if (node >= n_nodes) node = n_nodes - 1;   // clamp; stores guarded
            ah[mt] = *(const bf16x8*)(in + (size_t)node * DD + ks * 32 + q * 8);
        }
#pragma unroll
        for (int mt = 0; mt < 4; ++mt)
#pragma unroll
            for (int nt = 0; nt < 2; ++nt)
                acc[mt][nt] = __builtin_amdgcn_mfma_f32_16x16x32_bf16(bh[nt], ah[mt], acc[mt][nt], 0, 0, 0);
    }
    // out^T fragment: node = blk*64 + mt*16 + (lane&15); col = (w*2+nt)*16 + q*4 + reg
    unsigned short* base = half ? xr : xl;
    const float* bsrc = half ? br : bl;
#pragma unroll
    for (int nt = 0; nt < 2; ++nt) {
        int cm = (w * 2 + nt) * 16 + q * 4;          // column within [0,128)
        float4 bv = *(const float4*)(bsrc + cm);
#pragma unroll
        for (int mt = 0; mt < 4; ++mt) {
            int node = blk * 64 + mt * 16 + r;
            if (node < n_nodes) {
                uint2 o;
                o.x = pack2bf(acc[mt][nt][0] + bv.x, acc[mt][nt][1] + bv.y);
                o.y = pack2bf(acc[mt][nt][2] + bv.z, acc[mt][nt][3] + bv.w);
                *(uint2*)(base + (size_t)node * DD + cm) = o;
            }
        }
    }
}

// ---------------- per-node aggregation: plain-exp softmax, 4 edges/iter ----------
// EXACT round-2 body (45.2us verified optimum): 5 variants (VOP3P, sL-precompute
// x2, factored dots, 2-deep prefetch) all landed 49-62us. Balanced local optimum:
// VALU ~86% busy AND gather latency just-hidden. Do not touch.

__global__ __launch_bounds__(256) void k_node_agg(
    const unsigned short* __restrict__ xl, const unsigned short* __restrict__ xr,
    const int* __restrict__ row_ptr, const int* __restrict__ csr_src,
    const float* __restrict__ att, const float* __restrict__ bias,
    unsigned short* __restrict__ h_out, int n_nodes) {
    int wave = threadIdx.x >> 6;
    int lane = threadIdx.x & 63;
    int node = blockIdx.x * 4 + wave;
    if (node >= n_nodes) return;
    int grp = lane >> 4, sl = lane & 15;
    int beg = row_ptr[node], end = row_ptr[node + 1];

    uint4 xru = *(const uint4*)(xr + (size_t)node * DD + sl * 8);
    float xr0 = bflo(xru.x), xr1 = bfhi(xru.x), xr2 = bflo(xru.y), xr3 = bfhi(xru.y);
    float xr4 = bflo(xru.z), xr5 = bfhi(xru.z), xr6 = bflo(xru.w), xr7 = bfhi(xru.w);
    float4 at0 = *(const float4*)(att + sl * 8);
    float4 at1 = *(const float4*)(att + sl * 8 + 4);

    float l = 0.f;
    float a0 = 0.f, a1 = 0.f, a2 = 0.f, a3 = 0.f, a4 = 0.f, a5 = 0.f, a6 = 0.f, a7 = 0.f;

    int t0 = beg + grp;
    uint4 xu = make_uint4(0u, 0u, 0u, 0u);
    int sidx = 0;
    if (t0 < end) {
        int s = csr_src[t0];
        xu = *(const uint4*)(xl + (size_t)s * DD + sl * 8);
    }
    if (t0 + 4 < end) sidx = csr_src[t0 + 4];

    for (int t = t0; t < end; t += 4) {
        uint4 cur = xu;
        int snew = 0;
        if (t + 8 < end) snew = csr_src[t + 8];
        if (t + 4 < end) xu = *(const uint4*)(xl + (size_t)sidx * DD + sl * 8);
        sidx = snew;

        float x0 = bflo(cur.x), x1 = bfhi(cur.x), x2 = bflo(cur.y), x3 = bfhi(cur.y);
        float x4 = bflo(cur.z), x5 = bfhi(cur.z), x6 = bflo(cur.w), x7 = bfhi(cur.w);
        float v0 = x0 + xr0; v0 = v0 > 0.f ? v0 : NEG_SLOPE * v0;
        float v1 = x1 + xr1; v1 = v1 > 0.f ? v1 : NEG_SLOPE * v1;
        float v2 = x2 + xr2; v2 = v2 > 0.f ? v2 : NEG_SLOPE * v2;
        float v3 = x3 + xr3; v3 = v3 > 0.f ? v3 : NEG_SLOPE * v3;
        float v4 = x4 + xr4; v4 = v4 > 0.f ? v4 : NEG_SLOPE * v4;
        float v5 = x5 + xr5; v5 = v5 > 0.f ? v5 : NEG_SLOPE * v5;
        float v6 = x6 + xr6; v6 = v6 > 0.f ? v6 : NEG_SLOPE * v6;
        float v7 = x7 + xr7; v7 = v7 > 0.f ? v7 : NEG_SLOPE * v7;
        float lg = at0.x * v0 + at0.y * v1 + at0.z * v2 + at0.w * v3 +
                   at1.x * v4 + at1.y * v5 + at1.z * v6 + at1.w * v7;
        lg += __shfl_xor(lg, 1);           // head logit (lanes 2h,2h+1)
        float p = __expf(lg);
        l += p;
        a0 += p * x0; a1 += p * x1; a2 += p * x2; a3 += p * x3;
        a4 += p * x4; a5 += p * x5; a6 += p * x6; a7 += p * x7;
    }
    // merge the 4 edge-groups (plain sums)
    l  += __shfl_xor(l, 16);  l  += __shfl_xor(l, 32);
    a0 += __shfl_xor(a0, 16); a0 += __shfl_xor(a0, 32);
    a1 += __shfl_xor(a1, 16); a1 += __shfl_xor(a1, 32);
    a2 += __shfl_xor(a2, 16); a2 += __shfl_xor(a2, 32);
    a3 += __shfl_xor(a3, 16); a3 += __shfl_xor(a3, 32);
    a4 += __shfl_xor(a4, 16); a4 += __shfl_xor(a4, 32);
    a5 += __shfl_xor(a5, 16); a5 += __shfl_xor(a5, 32);
    a6 += __shfl_xor(a6, 16); a6 += __shfl_xor(a6, 32);
    a7 += __shfl_xor(a7, 16); a7 += __shfl_xor(a7, 32);

    if (grp == 0) {
        float4 bv0 = *(const float4*)(bias + sl * 8);
        float4 bv1 = *(const float4*)(bias + sl * 8 + 4);
        float rl = 1.f / l;
        float o0 = a0 * rl + bv0.x; o0 = o0 > 0.f ? o0 : __expf(o0) - 1.f;
        float o1 = a1 * rl + bv0.y; o1 = o1 > 0.f ? o1 : __expf(o1) - 1.f;
        float o2 = a2 * rl + bv0.z; o2 = o2 > 0.f ? o2 : __expf(o2) - 1.f;
        float o3 = a3 * rl + bv0.w; o3 = o3 > 0.f ? o3 : __expf(o3) - 1.f;
        float o4 = a4 * rl + bv1.x; o4 = o4 > 0.f ? o4 : __expf(o4) - 1.f;
        float o5 = a5 * rl + bv1.y; o5 = o5 > 0.f ? o5 : __expf(o5) - 1.f;
        float o6 = a6 * rl + bv1.z; o6 = o6 > 0.f ? o6 : __expf(o6) - 1.f;
        float o7 = a7 * rl + bv1.w; o7 = o7 > 0.f ? o7 : __expf(o7) - 1.f;
        uint4 o;
        o.x = pack2bf(o0, o1); o.y = pack2bf(o2, o3);
        o.z = pack2bf(o4, o5); o.w = pack2bf(o6, o7);
        *(uint4*)(h_out + (size_t)node * DD + sl * 8) = o;
    }
}

// ---------------- pooling + head ----------------

__global__ void k_pool2(const unsigned short* __restrict__ h, const int* __restrict__ batch,
                        float* __restrict__ pooled, float* __restrict__ counts,
                        int n_nodes, int chunk) {
    int c = threadIdx.x;               // 0..127
    int beg = blockIdx.x * chunk;
    if (beg >= n_nodes) return;
    int end = beg + chunk; if (end > n_nodes) end = n_nodes;
    int cur = batch[beg];
    float acc = 0.f; int cnt = 0;
    for (int node = beg; node < end; ++node) {
        int g = batch[node];
        if (g != cur) {
            atomicAdd(&pooled[cur * DD + c], acc);
            if (c == 0) atomicAdd(&counts[cur], (float)cnt);
            acc = 0.f; cnt = 0; cur = g;
        }
        acc += bf1(h[(size_t)node * DD + c]);
        cnt++;
    }
    atomicAdd(&pooled[cur * DD + c], acc);
    if (c == 0) atomicAdd(&counts[cur], (float)cnt);
}

__global__ void k_final(const float* __restrict__ pooled, const float* __restrict__ counts,
                        const float* __restrict__ Wout, const float* __restrict__ bout,
                        float* __restrict__ out) {
    __shared__ float slog[N_GRAPHS * N_CLASSES];
    int t = threadIdx.x;
    int g = t / N_CLASSES, c = t % N_CLASSES;
    float cnt = fmaxf(counts[g], 1.f);
    float acc = bout[c];
    for (int k = 0; k < DD; k++)
        acc += (pooled[g * DD + k] / cnt) * Wout[k * N_CLASSES + c];
    slog[t] = acc;
    __syncthreads();
    float mx = -INFINITY;
    for (int j = 0; j < N_CLASSES; j++) mx = fmaxf(mx, slog[g * N_CLASSES + j]);
    float se = 0.f;
    for (int j = 0; j < N_CLASSES; j++) se += __expf(slog[g * N_CLASSES + j] - mx);
    out[t] = acc - mx - __logf(se);
}

extern "C" void kernel_launch(void* const* d_in, const int* in_sizes, int n_in,
                              void* d_out, int out_size, void* d_ws, size_t ws_size,
                              hipStream_t stream) {
    const float* x     = (const float*)d_in[0];
    const int*   ei    = (const int*)d_in[1];
    const int*   batch = (const int*)d_in[2];
    const float* Wl    = (const float*)d_in[3];
    const float* bl    = (const float*)d_in[4];
    const float* Wr    = (const float*)d_in[5];
    const float* br    = (const float*)d_in[6];
    const float* att   = (const float*)d_in[7];
    const float* bias  = (const float*)d_in[8];
    const float* Wout  = (const float*)d_in[9];
    const float* bout  = (const float*)d_in[10];
    float* out = (float*)d_out;

    int n_nodes = in_sizes[0] / DD;    // 50000
    int n_edges = in_sizes[1] / 2;     // 800000
    int n_total = n_edges + n_nodes;   // 850000 (with self loops)
    int ND = n_nodes * DD;             // 6.4M

    const int WPL = 4 * 16 * 64 * 8;   // 32768 bf16 per layer
    unsigned long long bin_mul = (((unsigned long long)NBINS) << 32) / (unsigned)n_nodes;

    // workspace: hb | xb | xlb | xrb (bf16) | wB | cnt | btot | bin_start | binned |
    //            csr_src | row_ptr | pooled | counts
    unsigned short* hb  = (unsigned short*)d_ws;
    unsigned short* xb  = hb + (size_t)ND;
    unsigned short* xlb = xb + (size_t)ND;
    unsigned short* xrb = xlb + (size_t)ND;
    unsigned short* wB  = xrb + (size_t)ND;
    int*      cnt       = (int*)(wB + (size_t)N_LAYERS * WPL);
    int*      btot      = cnt + NBINS * 256;
    int*      bin_start = btot + NBINS;
    unsigned* binned    = (unsigned*)(bin_start + NBINS + 1);
    int*      csr_src   = (int*)(binned + n_total);
    int*      row_ptr   = csr_src + n_total;
    float*    pooled    = (float*)(row_ptr + n_nodes + 1);
    float*    counts    = pooled + N_GRAPHS * DD;

    dim3 b256(256);
    int gGemm = (n_nodes + 63) / 64;
    int gAgg  = (n_nodes + 3) / 4;
    int chunk = (n_total + 255) / 256;
    int poolBlocks = 1024;
    int poolChunk = (n_nodes + poolBlocks - 1) / poolBlocks;

    int n2 = ND / 2;
    int setupTotal = n2 + WCNT + N_GRAPHS * DD + N_GRAPHS;
    k_setup<<<(setupTotal + 255) / 256, b256, 0, stream>>>(x, (unsigned*)xb, Wl, Wr, wB,
                                                           pooled, counts, n2);
    k_bin_cnt<<<256, b256, 0, stream>>>(ei, cnt, n_edges, n_total, chunk, bin_mul);
    k_bin_scan<<<NBINS, b256, 0, stream>>>(cnt, btot);
    k_tot_scan<<<1, b256, 0, stream>>>(btot, bin_start, row_ptr, n_nodes);
    k_bin_scatter<<<256, b256, 0, stream>>>(ei, cnt, bin_start, binned, n_edges, n_total,
                                            chunk, bin_mul);
    k_bin_csr<<<NBINS, b256, 0, stream>>>(binned, bin_start, csr_src, row_ptr, n_nodes, bin_mul);

    for (int l = 0; l < N_LAYERS; l++) {
        const float* bl_l   = bl   + (size_t)l * DD;
        const float* br_l   = br   + (size_t)l * DD;
        const float* att_l  = att  + (size_t)l * HEADS * HID;
        const float* bias_l = bias + (size_t)l * DD;
        const unsigned short* in = (l == 0) ? xb : hb;

        k_gemm_mfma<<<dim3(gGemm, 2), b256, 0, stream>>>(in, wB + (size_t)l * WPL, bl_l, br_l,
                                                         xlb, xrb, n_nodes);
        k_node_agg<<<gAgg, b256, 0, stream>>>(xlb, xrb, row_ptr, csr_src, att_l, bias_l, hb, n_nodes);
    }

    k_pool2<<<poolBlocks, dim3(128), 0, stream>>>(hb, batch, pooled, counts, n_nodes, poolChunk);
    k_final<<<1, dim3(N_GRAPHS * N_CLASSES), 0, stream>>>(pooled, counts, Wout, bout, out);
}

// Round 8
// 461.936 us; speedup vs baseline: 1.0964x; 1.0235x over previous
//
#include <hip/hip_runtime.h>
#include <hip/hip_bf16.h>
#include <math.h>

#define DD 128
#define HEADS 8
#define HID 16
#define NEG_SLOPE 0.2f
#define N_LAYERS 5
#define N_GRAPHS 64
#define N_CLASSES 10
#define NBINS 256
#define BIN_CAP 8192

typedef __bf16 bf16x8 __attribute__((ext_vector_type(8)));
typedef float f32x4 __attribute__((ext_vector_type(4)));

__device__ __forceinline__ float bflo(unsigned u) { return __uint_as_float(u << 16); }
__device__ __forceinline__ float bfhi(unsigned u) { return __uint_as_float(u & 0xffff0000u); }
__device__ __forceinline__ float bf1(unsigned short us) { return __uint_as_float(((unsigned)us) << 16); }
// float -> bf16 (round-to-nearest-even), bit-twiddle; finite inputs only
__device__ __forceinline__ unsigned short f2bf(float f) {
    unsigned u = __float_as_uint(f);
    u += 0x7fffu + ((u >> 16) & 1u);
    return (unsigned short)(u >> 16);
}
__device__ __forceinline__ unsigned pack2bf(float a, float b) {
    return (unsigned)f2bf(a) | ((unsigned)f2bf(b) << 16);
}

#define WCNT (N_LAYERS * 4 * 16 * 64)   // wprep thread count (20480)

// ---------------- fused setup: convert x->bf16 | weight swizzle | zero pooled/counts ----

__global__ void k_setup(const float* __restrict__ x, unsigned* __restrict__ xb,
                        const float* __restrict__ Wl, const float* __restrict__ Wr,
                        unsigned short* __restrict__ wB,
                        float* __restrict__ pooled, float* __restrict__ counts, int n2) {
    int id = blockIdx.x * 256 + threadIdx.x;
    if (id < n2) {                                   // x -> bf16 (packed pairs)
        float2 v = *(const float2*)(x + 2 * (size_t)id);
        xb[id] = pack2bf(v.x, v.y);
        return;
    }
    id -= n2;
    if (id < WCNT) {                                 // weight swizzle
        int lane = id & 63;
        int ntg  = (id >> 6) & 15;
        int ks   = (id >> 10) & 3;
        int l    = id >> 12;
        int q = lane >> 4, r = lane & 15;
        int n = ntg * 16 + r;
        const float* W = ((n < DD) ? Wl : Wr) + (size_t)l * DD * DD;
        int nn = n & (DD - 1);
        size_t off = (size_t)l * (4 * 16 * 64 * 8) + ((size_t)(ks * 16 + ntg) * 64 + lane) * 8;
        for (int j = 0; j < 8; ++j) {
            int k = ks * 32 + q * 8 + j;
            wB[off + j] = f2bf(W[(size_t)k * DD + nn]);
        }
        return;
    }
    id -= WCNT;
    if (id < N_GRAPHS * DD) { pooled[id] = 0.f; return; }
    id -= N_GRAPHS * DD;
    if (id < N_GRAPHS) counts[id] = 0.f;
}

// ---------------- binned CSR build ----------------
// bin(d) = (d * bin_mul) >> 32 ; lo(b) = ceil(b*2^32 / bin_mul)

__global__ __launch_bounds__(256) void k_bin_cnt(const int* __restrict__ ei,
        int* __restrict__ cnt, int n_edges, int n_total, int chunk,
        unsigned long long bin_mul) {
    __shared__ int hist[NBINS];
    int tid = threadIdx.x;
    hist[tid] = 0;
    __syncthreads();
    int beg = blockIdx.x * chunk;
    int end = beg + chunk; if (end > n_total) end = n_total;
    for (int e = beg + tid; e < end; e += 256) {
        int d = (e < n_edges) ? ei[n_edges + e] : (e - n_edges);
        int b = (int)(((unsigned long long)(unsigned)d * bin_mul) >> 32);
        atomicAdd(&hist[b], 1);
    }
    __syncthreads();
    cnt[tid * 256 + blockIdx.x] = hist[tid];   // cnt[bin][blk]
}

// block per bin: exclusive scan of the 256 per-block counts (in place), emit bin total
__global__ __launch_bounds__(256) void k_bin_scan(int* __restrict__ cnt, int* __restrict__ btot) {
    __shared__ int wsum[4];
    int b = blockIdx.x, t = threadIdx.x, wv = t >> 6, ln = t & 63;
    int v = cnt[b * 256 + t];
    int x = v;
#pragma unroll
    for (int ofs = 1; ofs < 64; ofs <<= 1) {
        int tt = __shfl_up(x, ofs);
        if (ln >= ofs) x += tt;
    }
    if (ln == 63) wsum[wv] = x;
    __syncthreads();
    int off = 0;
    for (int k = 0; k < wv; k++) off += wsum[k];
    int incl = off + x;
    cnt[b * 256 + t] = incl - v;
    if (t == 255) btot[b] = incl;
}

// single block: exclusive scan of 256 bin totals -> bin_start[257]; row_ptr[n]=total
__global__ __launch_bounds__(256) void k_tot_scan(const int* __restrict__ btot,
        int* __restrict__ bin_start, int* __restrict__ row_ptr, int n_nodes) {
    __shared__ int wsum[4];
    int t = threadIdx.x, wv = t >> 6, ln = t & 63;
    int v = btot[t];
    int x = v;
#pragma unroll
    for (int ofs = 1; ofs < 64; ofs <<= 1) {
        int tt = __shfl_up(x, ofs);
        if (ln >= ofs) x += tt;
    }
    if (ln == 63) wsum[wv] = x;
    __syncthreads();
    int off = 0;
    for (int k = 0; k < wv; k++) off += wsum[k];
    int incl = off + x;
    bin_start[t] = incl - v;
    if (t == 255) { bin_start[256] = incl; row_ptr[n_nodes] = incl; }
}

// re-read edges, write packed (src | dst<<16) into per-(block,bin) contiguous runs
__global__ __launch_bounds__(256) void k_bin_scatter(const int* __restrict__ ei,
        const int* __restrict__ cnt, const int* __restrict__ bin_start,
        unsigned* __restrict__ binned, int n_edges, int n_total, int chunk,
        unsigned long long bin_mul) {
    __shared__ int cur[NBINS];
    int tid = threadIdx.x;
    cur[tid] = bin_start[tid] + cnt[tid * 256 + blockIdx.x];
    __syncthreads();
    int beg = blockIdx.x * chunk;
    int end = beg + chunk; if (end > n_total) end = n_total;
    for (int e = beg + tid; e < end; e += 256) {
        int s, d;
        if (e < n_edges) { s = ei[e]; d = ei[n_edges + e]; }
        else { s = d = e - n_edges; }
        int b = (int)(((unsigned long long)(unsigned)d * bin_mul) >> 32);
        int pos = atomicAdd(&cur[b], 1);
        binned[pos] = (unsigned)s | ((unsigned)d << 16);
    }
}

// block per bin: LDS degree count -> scan -> LDS scatter -> coalesced csr_src + row_ptr
__global__ __launch_bounds__(256) void k_bin_csr(const unsigned* __restrict__ binned,
        const int* __restrict__ bin_start, int* __restrict__ csr_src,
        int* __restrict__ row_ptr, int n_nodes, unsigned long long bin_mul) {
    __shared__ int sbuf[BIN_CAP];
    __shared__ int ldeg[256];
    __shared__ int wsum[4];
    int b = blockIdx.x, t = threadIdx.x, wv = t >> 6, ln = t & 63;
    int lo = (int)(((((unsigned long long)b) << 32) + bin_mul - 1) / bin_mul);
    int hi = (int)(((((unsigned long long)(b + 1)) << 32) + bin_mul - 1) / bin_mul);
    if (hi > n_nodes) hi = n_nodes;
    int estart = bin_start[b], eend = bin_start[b + 1];
    int ne = eend - estart;
    ldeg[t] = 0;
    __syncthreads();
    for (int k = t; k < ne; k += 256) {
        unsigned v = binned[estart + k];
        atomicAdd(&ldeg[(int)(v >> 16) - lo], 1);
    }
    __syncthreads();
    int vdeg = ldeg[t];
    int x = vdeg;
#pragma unroll
    for (int ofs = 1; ofs < 64; ofs <<= 1) {
        int tt = __shfl_up(x, ofs);
        if (ln >= ofs) x += tt;
    }
    if (ln == 63) wsum[wv] = x;
    __syncthreads();
    int off = 0;
    for (int k = 0; k < wv; k++) off += wsum[k];
    int excl = off + x - vdeg;
    if (lo + t < hi) row_ptr[lo + t] = estart + excl;
    ldeg[t] = excl;                      // reuse as cursor
    __syncthreads();
    for (int k = t; k < ne; k += 256) {
        unsigned v = binned[estart + k];
        int pos = atomicAdd(&ldeg[(int)(v >> 16) - lo], 1);
        sbuf[pos] = (int)(v & 0xffffu);
    }
    __syncthreads();
    for (int k = t; k < ne; k += 256)
        csr_src[estart + k] = sbuf[k];
}

// ---------------- MFMA GEMM (pure bf16): [xl|xr] = in @ [Wl|Wr] + [bl|br] -------
// Swapped operands (round-1 win): acc = mfma(W-frag, in-frag) = out^T.
// Round 7: one 512-thread block does BOTH halves (waves 0-3 xl, 4-7 xr) so `in`
// rows are fetched once per block; epilogue stages the 64x(2x128) bf16 tile in
// LDS and emits fully-coalesced uint4 stores (whole 128B lines per wave) --
// the 8B-granule scattered stores were the write-amplification suspect.

#define TPAD (DD + 8)    // LDS row stride in shorts: 272B, 16B-aligned rows

__global__ __launch_bounds__(512) void k_gemm_mfma(
    const unsigned short* __restrict__ in, const unsigned short* __restrict__ wB,
    const float* __restrict__ bl, const float* __restrict__ br,
    unsigned short* __restrict__ xl, unsigned short* __restrict__ xr, int n_nodes) {
    int w8 = threadIdx.x >> 6;           // 0..7
    int lane = threadIdx.x & 63;
    int q = lane >> 4, r = lane & 15;
    int half = w8 >> 2;                  // 0 = xl, 1 = xr
    int w = w8 & 3;
    int blk = blockIdx.x;

    __shared__ unsigned short tile[2][64][TPAD];

    f32x4 acc[4][2] = {};
#pragma unroll
    for (int ks = 0; ks < 4; ++ks) {
        bf16x8 bh[2];
#pragma unroll
        for (int nt = 0; nt < 2; ++nt) {
            int ntg = half * 8 + w * 2 + nt;         // 16-col group within [0,16)
            bh[nt] = *(const bf16x8*)(wB + ((size_t)(ks * 16 + ntg) * 64 + lane) * 8);
        }
        bf16x8 ah[4];
#pragma unroll
        for (int mt = 0; mt < 4; ++mt) {
            int node = blk * 64 + mt * 16 + r;
            if (node >= n_nodes) node = n_nodes - 1;   // clamp; stores guarded
            ah[mt] = *(const bf16x8*)(in + (size_t)node * DD + ks * 32 + q * 8);
        }
#pragma unroll
        for (int mt = 0; mt < 4; ++mt)
#pragma unroll
            for (int nt = 0; nt < 2; ++nt)
                acc[mt][nt] = __builtin_amdgcn_mfma_f32_16x16x32_bf16(bh[nt], ah[mt], acc[mt][nt], 0, 0, 0);
    }
    // out^T fragment -> LDS: node = mt*16 + r, col = (w*2+nt)*16 + q*4 + reg
    const float* bsrc = half ? br : bl;
#pragma unroll
    for (int nt = 0; nt < 2; ++nt) {
        int cm = (w * 2 + nt) * 16 + q * 4;          // column within [0,128)
        float4 bv = *(const float4*)(bsrc + cm);
#pragma unroll
        for (int mt = 0; mt < 4; ++mt) {
            uint2 o;
            o.x = pack2bf(acc[mt][nt][0] + bv.x, acc[mt][nt][1] + bv.y);
            o.y = pack2bf(acc[mt][nt][2] + bv.z, acc[mt][nt][3] + bv.w);
            *(uint2*)&tile[half][mt * 16 + r][cm] = o;
        }
    }
    __syncthreads();
    // coalesced store: 2 halves x 64 nodes x 16 uint4 chunks = 2048 chunks
    int t = threadIdx.x;
#pragma unroll
    for (int i = 0; i < 4; ++i) {
        int flat = i * 512 + t;          // 0..2047
        int hsel = flat >> 10;
        int rem = flat & 1023;
        int nd = rem >> 4;               // 0..63
        int ch = rem & 15;               // 0..15 (16B chunk)
        int node = blk * 64 + nd;
        if (node < n_nodes) {
            uint4 v = *(const uint4*)&tile[hsel][nd][ch * 8];
            unsigned short* dst = hsel ? xr : xl;
            *(uint4*)(dst + (size_t)node * DD + ch * 8) = v;
        }
    }
}

// ---------------- per-node aggregation: plain-exp softmax, 4 edges/iter ----------
// EXACT round-2 body (45.2us verified optimum): 5 variants (VOP3P, sL-precompute
// x2, factored dots, 2-deep prefetch) all landed 49-62us. Balanced local optimum:
// VALU ~86% busy AND gather latency just-hidden. Do not touch.

__global__ __launch_bounds__(256) void k_node_agg(
    const unsigned short* __restrict__ xl, const unsigned short* __restrict__ xr,
    const int* __restrict__ row_ptr, const int* __restrict__ csr_src,
    const float* __restrict__ att, const float* __restrict__ bias,
    unsigned short* __restrict__ h_out, int n_nodes) {
    int wave = threadIdx.x >> 6;
    int lane = threadIdx.x & 63;
    int node = blockIdx.x * 4 + wave;
    if (node >= n_nodes) return;
    int grp = lane >> 4, sl = lane & 15;
    int beg = row_ptr[node], end = row_ptr[node + 1];

    uint4 xru = *(const uint4*)(xr + (size_t)node * DD + sl * 8);
    float xr0 = bflo(xru.x), xr1 = bfhi(xru.x), xr2 = bflo(xru.y), xr3 = bfhi(xru.y);
    float xr4 = bflo(xru.z), xr5 = bfhi(xru.z), xr6 = bflo(xru.w), xr7 = bfhi(xru.w);
    float4 at0 = *(const float4*)(att + sl * 8);
    float4 at1 = *(const float4*)(att + sl * 8 + 4);

    float l = 0.f;
    float a0 = 0.f, a1 = 0.f, a2 = 0.f, a3 = 0.f, a4 = 0.f, a5 = 0.f, a6 = 0.f, a7 = 0.f;

    int t0 = beg + grp;
    uint4 xu = make_uint4(0u, 0u, 0u, 0u);
    int sidx = 0;
    if (t0 < end) {
        int s = csr_src[t0];
        xu = *(const uint4*)(xl + (size_t)s * DD + sl * 8);
    }
    if (t0 + 4 < end) sidx = csr_src[t0 + 4];

    for (int t = t0; t < end; t += 4) {
        uint4 cur = xu;
        int snew = 0;
        if (t + 8 < end) snew = csr_src[t + 8];
        if (t + 4 < end) xu = *(const uint4*)(xl + (size_t)sidx * DD + sl * 8);
        sidx = snew;

        float x0 = bflo(cur.x), x1 = bfhi(cur.x), x2 = bflo(cur.y), x3 = bfhi(cur.y);
        float x4 = bflo(cur.z), x5 = bfhi(cur.z), x6 = bflo(cur.w), x7 = bfhi(cur.w);
        float v0 = x0 + xr0; v0 = v0 > 0.f ? v0 : NEG_SLOPE * v0;
        float v1 = x1 + xr1; v1 = v1 > 0.f ? v1 : NEG_SLOPE * v1;
        float v2 = x2 + xr2; v2 = v2 > 0.f ? v2 : NEG_SLOPE * v2;
        float v3 = x3 + xr3; v3 = v3 > 0.f ? v3 : NEG_SLOPE * v3;
        float v4 = x4 + xr4; v4 = v4 > 0.f ? v4 : NEG_SLOPE * v4;
        float v5 = x5 + xr5; v5 = v5 > 0.f ? v5 : NEG_SLOPE * v5;
        float v6 = x6 + xr6; v6 = v6 > 0.f ? v6 : NEG_SLOPE * v6;
        float v7 = x7 + xr7; v7 = v7 > 0.f ? v7 : NEG_SLOPE * v7;
        float lg = at0.x * v0 + at0.y * v1 + at0.z * v2 + at0.w * v3 +
                   at1.x * v4 + at1.y * v5 + at1.z * v6 + at1.w * v7;
        lg += __shfl_xor(lg, 1);           // head logit (lanes 2h,2h+1)
        float p = __expf(lg);
        l += p;
        a0 += p * x0; a1 += p * x1; a2 += p * x2; a3 += p * x3;
        a4 += p * x4; a5 += p * x5; a6 += p * x6; a7 += p * x7;
    }
    // merge the 4 edge-groups (plain sums)
    l  += __shfl_xor(l, 16);  l  += __shfl_xor(l, 32);
    a0 += __shfl_xor(a0, 16); a0 += __shfl_xor(a0, 32);
    a1 += __shfl_xor(a1, 16); a1 += __shfl_xor(a1, 32);
    a2 += __shfl_xor(a2, 16); a2 += __shfl_xor(a2, 32);
    a3 += __shfl_xor(a3, 16); a3 += __shfl_xor(a3, 32);
    a4 += __shfl_xor(a4, 16); a4 += __shfl_xor(a4, 32);
    a5 += __shfl_xor(a5, 16); a5 += __shfl_xor(a5, 32);
    a6 += __shfl_xor(a6, 16); a6 += __shfl_xor(a6, 32);
    a7 += __shfl_xor(a7, 16); a7 += __shfl_xor(a7, 32);

    if (grp == 0) {
        float4 bv0 = *(const float4*)(bias + sl * 8);
        float4 bv1 = *(const float4*)(bias + sl * 8 + 4);
        float rl = 1.f / l;
        float o0 = a0 * rl + bv0.x; o0 = o0 > 0.f ? o0 : __expf(o0) - 1.f;
        float o1 = a1 * rl + bv0.y; o1 = o1 > 0.f ? o1 : __expf(o1) - 1.f;
        float o2 = a2 * rl + bv0.z; o2 = o2 > 0.f ? o2 : __expf(o2) - 1.f;
        float o3 = a3 * rl + bv0.w; o3 = o3 > 0.f ? o3 : __expf(o3) - 1.f;
        float o4 = a4 * rl + bv1.x; o4 = o4 > 0.f ? o4 : __expf(o4) - 1.f;
        float o5 = a5 * rl + bv1.y; o5 = o5 > 0.f ? o5 : __expf(o5) - 1.f;
        float o6 = a6 * rl + bv1.z; o6 = o6 > 0.f ? o6 : __expf(o6) - 1.f;
        float o7 = a7 * rl + bv1.w; o7 = o7 > 0.f ? o7 : __expf(o7) - 1.f;
        uint4 o;
        o.x = pack2bf(o0, o1); o.y = pack2bf(o2, o3);
        o.z = pack2bf(o4, o5); o.w = pack2bf(o6, o7);
        *(uint4*)(h_out + (size_t)node * DD + sl * 8) = o;
    }
}

// ---------------- pooling + head ----------------

__global__ void k_pool2(const unsigned short* __restrict__ h, const int* __restrict__ batch,
                        float* __restrict__ pooled, float* __restrict__ counts,
                        int n_nodes, int chunk) {
    int c = threadIdx.x;               // 0..127
    int beg = blockIdx.x * chunk;
    if (beg >= n_nodes) return;
    int end = beg + chunk; if (end > n_nodes) end = n_nodes;
    int cur = batch[beg];
    float acc = 0.f; int cnt = 0;
    for (int node = beg; node < end; ++node) {
        int g = batch[node];
        if (g != cur) {
            atomicAdd(&pooled[cur * DD + c], acc);
            if (c == 0) atomicAdd(&counts[cur], (float)cnt);
            acc = 0.f; cnt = 0; cur = g;
        }
        acc += bf1(h[(size_t)node * DD + c]);
        cnt++;
    }
    atomicAdd(&pooled[cur * DD + c], acc);
    if (c == 0) atomicAdd(&counts[cur], (float)cnt);
}

__global__ void k_final(const float* __restrict__ pooled, const float* __restrict__ counts,
                        const float* __restrict__ Wout, const float* __restrict__ bout,
                        float* __restrict__ out) {
    __shared__ float slog[N_GRAPHS * N_CLASSES];
    int t = threadIdx.x;
    int g = t / N_CLASSES, c = t % N_CLASSES;
    float cnt = fmaxf(counts[g], 1.f);
    float acc = bout[c];
    for (int k = 0; k < DD; k++)
        acc += (pooled[g * DD + k] / cnt) * Wout[k * N_CLASSES + c];
    slog[t] = acc;
    __syncthreads();
    float mx = -INFINITY;
    for (int j = 0; j < N_CLASSES; j++) mx = fmaxf(mx, slog[g * N_CLASSES + j]);
    float se = 0.f;
    for (int j = 0; j < N_CLASSES; j++) se += __expf(slog[g * N_CLASSES + j] - mx);
    out[t] = acc - mx - __logf(se);
}

extern "C" void kernel_launch(void* const* d_in, const int* in_sizes, int n_in,
                              void* d_out, int out_size, void* d_ws, size_t ws_size,
                              hipStream_t stream) {
    const float* x     = (const float*)d_in[0];
    const int*   ei    = (const int*)d_in[1];
    const int*   batch = (const int*)d_in[2];
    const float* Wl    = (const float*)d_in[3];
    const float* bl    = (const float*)d_in[4];
    const float* Wr    = (const float*)d_in[5];
    const float* br    = (const float*)d_in[6];
    const float* att   = (const float*)d_in[7];
    const float* bias  = (const float*)d_in[8];
    const float* Wout  = (const float*)d_in[9];
    const float* bout  = (const float*)d_in[10];
    float* out = (float*)d_out;

    int n_nodes = in_sizes[0] / DD;    // 50000
    int n_edges = in_sizes[1] / 2;     // 800000
    int n_total = n_edges + n_nodes;   // 850000 (with self loops)
    int ND = n_nodes * DD;             // 6.4M

    const int WPL = 4 * 16 * 64 * 8;   // 32768 bf16 per layer
    unsigned long long bin_mul = (((unsigned long long)NBINS) << 32) / (unsigned)n_nodes;

    // workspace: hb | xb | xlb | xrb (bf16) | wB | cnt | btot | bin_start | binned |
    //            csr_src | row_ptr | pooled | counts
    unsigned short* hb  = (unsigned short*)d_ws;
    unsigned short* xb  = hb + (size_t)ND;
    unsigned short* xlb = xb + (size_t)ND;
    unsigned short* xrb = xlb + (size_t)ND;
    unsigned short* wB  = xrb + (size_t)ND;
    int*      cnt       = (int*)(wB + (size_t)N_LAYERS * WPL);
    int*      btot      = cnt + NBINS * 256;
    int*      bin_start = btot + NBINS;
    unsigned* binned    = (unsigned*)(bin_start + NBINS + 1);
    int*      csr_src   = (int*)(binned + n_total);
    int*      row_ptr   = csr_src + n_total;
    float*    pooled    = (float*)(row_ptr + n_nodes + 1);
    float*    counts    = pooled + N_GRAPHS * DD;

    dim3 b256(256);
    int gGemm = (n_nodes + 63) / 64;
    int gAgg  = (n_nodes + 3) / 4;
    int chunk = (n_total + 255) / 256;
    int poolBlocks = 1024;
    int poolChunk = (n_nodes + poolBlocks - 1) / poolBlocks;

    int n2 = ND / 2;
    int setupTotal = n2 + WCNT + N_GRAPHS * DD + N_GRAPHS;
    k_setup<<<(setupTotal + 255) / 256, b256, 0, stream>>>(x, (unsigned*)xb, Wl, Wr, wB,
                                                           pooled, counts, n2);
    k_bin_cnt<<<256, b256, 0, stream>>>(ei, cnt, n_edges, n_total, chunk, bin_mul);
    k_bin_scan<<<NBINS, b256, 0, stream>>>(cnt, btot);
    k_tot_scan<<<1, b256, 0, stream>>>(btot, bin_start, row_ptr, n_nodes);
    k_bin_scatter<<<256, b256, 0, stream>>>(ei, cnt, bin_start, binned, n_edges, n_total,
                                            chunk, bin_mul);
    k_bin_csr<<<NBINS, b256, 0, stream>>>(binned, bin_start, csr_src, row_ptr, n_nodes, bin_mul);

    for (int l = 0; l < N_LAYERS; l++) {
        const float* bl_l   = bl   + (size_t)l * DD;
        const float* br_l   = br   + (size_t)l * DD;
        const float* att_l  = att  + (size_t)l * HEADS * HID;
        const float* bias_l = bias + (size_t)l * DD;
        const unsigned short* in = (l == 0) ? xb : hb;

        k_gemm_mfma<<<gGemm, dim3(512), 0, stream>>>(in, wB + (size_t)l * WPL, bl_l, br_l,
                                                     xlb, xrb, n_nodes);
        k_node_agg<<<gAgg, b256, 0, stream>>>(xlb, xrb, row_ptr, csr_src, att_l, bias_l, hb, n_nodes);
    }

    k_pool2<<<poolBlocks, dim3(128), 0, stream>>>(hb, batch, pooled, counts, n_nodes, poolChunk);
    k_final<<<1, dim3(N_GRAPHS * N_CLASSES), 0, stream>>>(pooled, counts, Wout, bout, out);
}